// Round 1
// baseline (593.149 us; speedup 1.0000x reference)
//
#include <hip/hip_runtime.h>

#define LSEQ 2048
#define DMODEL 1024
#define INNER 2048

typedef short short8 __attribute__((ext_vector_type(8)));
typedef float f32x4 __attribute__((ext_vector_type(4)));

__device__ __forceinline__ unsigned short f2bf(float f) {
    unsigned u = __builtin_bit_cast(unsigned, f);
    u += 0x7fffu + ((u >> 16) & 1u);
    return (unsigned short)(u >> 16);
}

__device__ __forceinline__ float softplus_f(float x) {
    return fmaxf(x, 0.f) + log1pf(__expf(-fabsf(x)));
}
__device__ __forceinline__ float silu_f(float x) {
    return x / (1.f + __expf(-x));
}

// C[m,n] = sum_k A[m,k] * W[n,k]; optional epilogue mode==1: softplus(softplus(v + bias[n]))
// Tiles: 128x128, BK=32, 256 threads = 4 waves (2x2), each wave 4x4 subtiles of 16x16.
__global__ __launch_bounds__(256) void gemm_bt(
    const float* __restrict__ A, int lda,
    const float* __restrict__ W, int ldw,
    float* __restrict__ C, int ldc,
    int K, const float* __restrict__ bias, int n_store, int mode)
{
    __shared__ short As[128 * 40];   // +8 pad per 32-k row to break bank conflicts
    __shared__ short Ws[128 * 40];
    const int t    = threadIdx.x;
    const int bm   = blockIdx.y, bn = blockIdx.x;
    const int lane = t & 63, quad = lane >> 4, lr = lane & 15;
    const int wv   = t >> 6;
    const int wm   = (wv >> 1) * 64, wn = (wv & 1) * 64;

    const int sr = t >> 3;          // 0..31 staging row
    const int sc = (t & 7) << 2;    // float4 col 0,4,...,28
    const float* Ab = A + (size_t)(bm * 128) * lda;
    const float* Wb = W + (size_t)(bn * 128) * ldw;

    f32x4 acc[4][4];
    #pragma unroll
    for (int i = 0; i < 4; ++i)
        #pragma unroll
        for (int j = 0; j < 4; ++j)
            acc[i][j] = (f32x4){0.f, 0.f, 0.f, 0.f};

    const int nk = K >> 5;
    for (int kb = 0; kb < nk; ++kb) {
        const int k0 = kb << 5;
        #pragma unroll
        for (int i = 0; i < 4; ++i) {
            int row = sr + i * 32;
            float4 av = *(const float4*)(Ab + (size_t)row * lda + k0 + sc);
            float4 wv4 = *(const float4*)(Wb + (size_t)row * ldw + k0 + sc);
            ushort4 a4, w4;
            a4.x = f2bf(av.x); a4.y = f2bf(av.y); a4.z = f2bf(av.z); a4.w = f2bf(av.w);
            w4.x = f2bf(wv4.x); w4.y = f2bf(wv4.y); w4.z = f2bf(wv4.z); w4.w = f2bf(wv4.w);
            *(ushort4*)&As[row * 40 + sc] = a4;
            *(ushort4*)&Ws[row * 40 + sc] = w4;
        }
        __syncthreads();
        short8 af[4], bfr[4];
        #pragma unroll
        for (int mi = 0; mi < 4; ++mi)
            af[mi] = *(const short8*)&As[(wm + mi * 16 + lr) * 40 + quad * 8];
        #pragma unroll
        for (int ni = 0; ni < 4; ++ni)
            bfr[ni] = *(const short8*)&Ws[(wn + ni * 16 + lr) * 40 + quad * 8];
        #pragma unroll
        for (int mi = 0; mi < 4; ++mi)
            #pragma unroll
            for (int ni = 0; ni < 4; ++ni)
                acc[mi][ni] = __builtin_amdgcn_mfma_f32_16x16x32_bf16(af[mi], bfr[ni], acc[mi][ni], 0, 0, 0);
        __syncthreads();
    }

    #pragma unroll
    for (int mi = 0; mi < 4; ++mi) {
        #pragma unroll
        for (int ni = 0; ni < 4; ++ni) {
            int col = bn * 128 + wn + ni * 16 + lr;
            #pragma unroll
            for (int p = 0; p < 4; ++p) {
                int row = bm * 128 + wm + mi * 16 + quad * 4 + p;
                float v = acc[mi][ni][p];
                if (mode == 1) v = softplus_f(softplus_f(v + bias[col]));
                if (col < n_store) C[(size_t)row * ldc + col] = v;
            }
        }
    }
}

__global__ __launch_bounds__(256) void pad_wx(const float* __restrict__ Wx, float* __restrict__ Wxp) {
    int i = blockIdx.x * 256 + threadIdx.x;       // 128*2048
    int row = i >> 11;
    int col = i & 2047;
    Wxp[i] = (row < 96) ? Wx[row * 2048 + col] : 0.f;
}

// causal depthwise conv (taps 4) + bias + silu;  xr cols 0..2047 -> xs (compact, width 2048)
__global__ __launch_bounds__(256) void conv_silu_k(
    const float* __restrict__ xr, const float* __restrict__ cw,
    const float* __restrict__ cb, float* __restrict__ xs)
{
    int idx = blockIdx.x * 256 + threadIdx.x;     // B*L*INNER = 8,388,608
    int d = idx & 2047;
    int t = (idx >> 11) & 2047;
    int b = idx >> 22;
    const float* base = xr + ((size_t)b * LSEQ) * 4096 + d;
    float acc = cb[d];
    float w0 = cw[d * 4 + 0], w1 = cw[d * 4 + 1], w2 = cw[d * 4 + 2], w3 = cw[d * 4 + 3];
    acc += w3 * base[(size_t)t * 4096];
    if (t >= 1) acc += w2 * base[(size_t)(t - 1) * 4096];
    if (t >= 2) acc += w1 * base[(size_t)(t - 2) * 4096];
    if (t >= 3) acc += w0 * base[(size_t)(t - 3) * 4096];
    xs[idx] = silu_f(acc);
}

// chunked linear scan, chunk len 64, 32 chunks. Phase1: per-chunk P (via exp(A*sum dt)) and local S.
__global__ __launch_bounds__(256) void scan_p1(
    const float* __restrict__ dt2,   // stride 4096 (stored in xr cols 0..2047)
    const float* __restrict__ xs,
    const float* __restrict__ xdbl,
    const float* __restrict__ A_log,
    float* __restrict__ csP, float* __restrict__ csS)
{
    const int tid = threadIdx.x;
    const int d  = blockIdx.x * 256 + tid;
    const int ch = blockIdx.y;
    const int b  = blockIdx.z;
    const int r0 = b * LSEQ + ch * 64;
    __shared__ float sB[64 * 16];
    for (int i = tid; i < 1024; i += 256) {
        int tt = i >> 4, n = i & 15;
        sB[i] = xdbl[(size_t)(r0 + tt) * 96 + 64 + n];
    }
    __syncthreads();
    float an[16], h[16];
    #pragma unroll
    for (int n = 0; n < 16; ++n) {
        an[n] = -__expf(A_log[d * 16 + n]);
        h[n] = 0.f;
    }
    float sdt = 0.f;
    for (int tt = 0; tt < 64; ++tt) {
        size_t r = (size_t)(r0 + tt);
        float dtv = dt2[r * 4096 + d];
        float xv  = xs[r * 2048 + d];
        float dx = dtv * xv;
        sdt += dtv;
        #pragma unroll
        for (int n = 0; n < 16; ++n) {
            float e = __expf(dtv * an[n]);
            h[n] = e * h[n] + dx * sB[tt * 16 + n];
        }
    }
    size_t o = ((size_t)b * 32 + ch) * 32768 + (size_t)d * 16;
    #pragma unroll
    for (int n = 0; n < 16; ++n) {
        csP[o + n] = __expf(an[n] * sdt);
        csS[o + n] = h[n];
    }
}

// Phase2: sequential combine over 32 chunks; rewrites csS with per-chunk initial h.
__global__ __launch_bounds__(256) void scan_p2(
    const float* __restrict__ csP, float* __restrict__ csS)
{
    int i = blockIdx.x * 256 + threadIdx.x;   // 2*2048*16 = 65536
    int b = i >> 15;
    int j = i & 32767;
    float h = 0.f;
    for (int ch = 0; ch < 32; ++ch) {
        size_t o = ((size_t)b * 32 + ch) * 32768 + j;
        float p = csP[o];
        float s = csS[o];
        csS[o] = h;         // h at chunk start
        h = p * h + s;
    }
}

// Phase3: replay with correct h-init, produce y, fuse (y + xs*D)*silu(res) -> overwrite xs
__global__ __launch_bounds__(256) void scan_p3(
    const float* __restrict__ xr,    // dt2 at col d, res at col 2048+d
    float* __restrict__ xs,
    const float* __restrict__ xdbl,
    const float* __restrict__ A_log,
    const float* __restrict__ Dp,
    const float* __restrict__ hin)   // csS (now h-inits)
{
    const int tid = threadIdx.x;
    const int d  = blockIdx.x * 256 + tid;
    const int ch = blockIdx.y;
    const int b  = blockIdx.z;
    const int r0 = b * LSEQ + ch * 64;
    __shared__ float sBC[64 * 32];
    for (int i = tid; i < 2048; i += 256) {
        int tt = i >> 5, c = i & 31;
        sBC[i] = xdbl[(size_t)(r0 + tt) * 96 + 64 + c];
    }
    __syncthreads();
    float an[16], h[16];
    size_t o = ((size_t)b * 32 + ch) * 32768 + (size_t)d * 16;
    #pragma unroll
    for (int n = 0; n < 16; ++n) {
        an[n] = -__expf(A_log[d * 16 + n]);
        h[n] = hin[o + n];
    }
    const float Dv = Dp[d];
    for (int tt = 0; tt < 64; ++tt) {
        size_t r = (size_t)(r0 + tt);
        float dtv  = xr[r * 4096 + d];
        float resv = xr[r * 4096 + 2048 + d];
        float xv   = xs[r * 2048 + d];
        float dx = dtv * xv;
        float y = 0.f;
        #pragma unroll
        for (int n = 0; n < 16; ++n) {
            float e = __expf(dtv * an[n]);
            h[n] = e * h[n] + dx * sBC[tt * 32 + n];
            y += h[n] * sBC[tt * 32 + 16 + n];
        }
        xs[r * 2048 + d] = (y + xv * Dv) * silu_f(resv);
    }
}

extern "C" void kernel_launch(void* const* d_in, const int* in_sizes, int n_in,
                              void* d_out, int out_size, void* d_ws, size_t ws_size,
                              hipStream_t stream)
{
    const float* x     = (const float*)d_in[0];
    const float* W_in  = (const float*)d_in[1];
    const float* cw    = (const float*)d_in[2];
    const float* cb    = (const float*)d_in[3];
    const float* W_x   = (const float*)d_in[4];
    const float* W_dt  = (const float*)d_in[5];
    const float* b_dt  = (const float*)d_in[6];
    const float* A_log = (const float*)d_in[7];
    const float* Dp    = (const float*)d_in[8];
    const float* W_out = (const float*)d_in[9];
    float* out = (float*)d_out;

    float* ws   = (float*)d_ws;
    float* xr   = ws;                 // (B*L, 4096): xs_raw | res; cols 0..2047 reused for dt2
    float* xs   = ws + 16777216;      // (B*L, 2048): conv-silu xs, later gated y
    float* xdbl = ws + 25165824;      // (B*L, 96)
    float* wxp  = ws + 25559040;      // (128, 2048) zero-padded W_x
    float* csP  = ws + 25821184;      // (B, 32, 2048*16)
    float* csS  = ws + 27918336;      // (B, 32, 2048*16)

    dim3 blk(256);
    // 1) xr = x @ W_in^T   (M=4096, N=4096, K=1024)
    gemm_bt<<<dim3(32, 32), blk, 0, stream>>>(x, 1024, W_in, 1024, xr, 4096, 1024, nullptr, 4096, 0);
    // pad W_x (96 -> 128 rows)
    pad_wx<<<dim3(1024), blk, 0, stream>>>(W_x, wxp);
    // 2) conv + silu -> xs
    conv_silu_k<<<dim3(32768), blk, 0, stream>>>(xr, cw, cb, xs);
    // 3) x_dbl = xs @ W_x^T   (M=4096, N=128(pad, store 96), K=2048)
    gemm_bt<<<dim3(1, 32), blk, 0, stream>>>(xs, 2048, wxp, 2048, xdbl, 96, 2048, nullptr, 96, 0);
    // 4) dt2 = sp(sp(xdbl[:, :64] @ W_dt^T + b_dt)) -> xr cols 0..2047 (ldc=4096)
    gemm_bt<<<dim3(16, 32), blk, 0, stream>>>(xdbl, 96, W_dt, 64, xr, 4096, 64, b_dt, 2048, 1);
    // 5) chunked selective scan (+ fused gating into xs)
    scan_p1<<<dim3(8, 32, 2), blk, 0, stream>>>(xr, xs, xdbl, A_log, csP, csS);
    scan_p2<<<dim3(256), blk, 0, stream>>>(csP, csS);
    scan_p3<<<dim3(8, 32, 2), blk, 0, stream>>>(xr, xs, xdbl, A_log, Dp, csS);
    // 6) out = y @ W_out^T   (M=4096, N=1024, K=2048)
    gemm_bt<<<dim3(8, 32), blk, 0, stream>>>(xs, 2048, W_out, 2048, out, 1024, 2048, nullptr, 1024, 0);
}